// Round 3
// baseline (10836.842 us; speedup 1.0000x reference)
//
#include <hip/hip_runtime.h>
#include <hip/hip_bf16.h>

// Problem constants
#define T_LEN 2048
#define E_DIM 512
#define H_DIM 256
#define K_TAG 48
#define START_TAG 46
#define END_TAG 47
#define NEG_VAL -10000.0f

// ---------------------------------------------------------------------------
// GEMM: out[d][t][row] = dot(A[t][0:512], W[d*1024+row][0:512]) + bih[n]+bhh[n]
// A is either x (2048x512) or gathered embedding rows (useGather).
// W = wih for one layer, flattened (2048 rows x 512).
// out index: ((d*2048 + t)<<10) + row   (n = d*1024+row)
// ---------------------------------------------------------------------------
__global__ __launch_bounds__(256) void gemm_xg(
    const float* __restrict__ Abase, const int* __restrict__ sent,
    const float* __restrict__ Bw, const float* __restrict__ bih,
    const float* __restrict__ bhh, float* __restrict__ out, int useGather)
{
    __shared__ float As[16][68];
    __shared__ float Bs[16][68];
    const int tx = threadIdx.x & 15, ty = threadIdx.x >> 4;
    const int t0 = blockIdx.y * 64, n0 = blockIdx.x * 64;
    // staging: thread -> (row r, 4 consecutive k)
    const int r  = threadIdx.x >> 2;        // 0..63
    const int kq = (threadIdx.x & 3) * 4;   // 0,4,8,12
    const float* arow;
    if (useGather) arow = Abase + (size_t)sent[t0 + r] * 512 + kq;
    else           arow = Abase + (size_t)(t0 + r) * 512 + kq;
    const float* brow = Bw + (size_t)(n0 + r) * 512 + kq;

    float acc[4][4];
#pragma unroll
    for (int i = 0; i < 4; i++)
#pragma unroll
        for (int j = 0; j < 4; j++) acc[i][j] = 0.f;

    for (int k0 = 0; k0 < 512; k0 += 16) {
        float4 a4 = *(const float4*)(arow + k0);
        float4 b4 = *(const float4*)(brow + k0);
        __syncthreads();
        As[kq+0][r] = a4.x; As[kq+1][r] = a4.y; As[kq+2][r] = a4.z; As[kq+3][r] = a4.w;
        Bs[kq+0][r] = b4.x; Bs[kq+1][r] = b4.y; Bs[kq+2][r] = b4.z; Bs[kq+3][r] = b4.w;
        __syncthreads();
#pragma unroll
        for (int k = 0; k < 16; k++) {
            float4 av = *(const float4*)&As[k][ty*4];
            float4 bv = *(const float4*)&Bs[k][tx*4];
            acc[0][0] = fmaf(av.x, bv.x, acc[0][0]); acc[0][1] = fmaf(av.x, bv.y, acc[0][1]);
            acc[0][2] = fmaf(av.x, bv.z, acc[0][2]); acc[0][3] = fmaf(av.x, bv.w, acc[0][3]);
            acc[1][0] = fmaf(av.y, bv.x, acc[1][0]); acc[1][1] = fmaf(av.y, bv.y, acc[1][1]);
            acc[1][2] = fmaf(av.y, bv.z, acc[1][2]); acc[1][3] = fmaf(av.y, bv.w, acc[1][3]);
            acc[2][0] = fmaf(av.z, bv.x, acc[2][0]); acc[2][1] = fmaf(av.z, bv.y, acc[2][1]);
            acc[2][2] = fmaf(av.z, bv.z, acc[2][2]); acc[2][3] = fmaf(av.z, bv.w, acc[2][3]);
            acc[3][0] = fmaf(av.w, bv.x, acc[3][0]); acc[3][1] = fmaf(av.w, bv.y, acc[3][1]);
            acc[3][2] = fmaf(av.w, bv.z, acc[3][2]); acc[3][3] = fmaf(av.w, bv.w, acc[3][3]);
        }
    }
#pragma unroll
    for (int i = 0; i < 4; i++) {
        int t = t0 + ty*4 + i;
#pragma unroll
        for (int j = 0; j < 4; j++) {
            int n = n0 + tx*4 + j;
            float b = bih[n] + bhh[n];
            out[((size_t)((n >> 10) * 2048 + t) << 10) + (n & 1023)] = acc[i][j] + b;
        }
    }
}

// ---------------------------------------------------------------------------
// LSTM recurrence. Grid = 8 blocks: d = bx>>2 (0 fwd, 1 bwd), b = bx&3 (quad).
// Block owns 64 hidden units [64b,64b+64). wave w: gate g=w>>2, h-chunk c=w&3.
// Weights (256 rows x 256 cols fp32 = 256KB) live in VGPRs (64/thread).
//
// OCCUPANCY/VGPR HISTORY:
//   R0: __launch_bounds__(1024)    -> VGPR_Count=56, wr[] spilled, 1.92us/step
//   R1: __launch_bounds__(1024,4)  -> STILL 56. HIP's 2nd arg is only a MIN
//       waves/EU (caps budget at 128) -- the occupancy heuristic still targeted
//       8 waves/EU and allocated 56.
//   R2: amdgpu_waves_per_eu(4,4) pins min AND max -> extra occupancy impossible
//       -> allocator free to use the full 128-VGPR budget, wr[] stays resident.
// Cross-block h exchange: tagged {h,step} 8B relaxed AGENT atomics, 2 slots.
// ---------------------------------------------------------------------------
__global__ __launch_bounds__(1024)
__attribute__((amdgpu_waves_per_eu(4, 4)))
void lstm_pass(
    const float* __restrict__ xg,   // (2, T, 1024) for this layer
    const float* __restrict__ whh,  // (2, 1024, 256) for this layer
    float* __restrict__ xout,       // (T, 512) concat [hf, hb]
    unsigned long long* __restrict__ pairs) // (2 dirs, 2 slots, 256)
{
    const int tid = threadIdx.x;
    const int w = tid >> 6, L = tid & 63;
    const int d = blockIdx.x >> 2, b = blockIdx.x & 3;
    const int g = w >> 2, c = w & 3;

    __shared__ __align__(16) float stage[2][256];
    __shared__ float parts[16][64];

    // weight preload: row = g*256 + b*64 + L, cols [c*64, c*64+64)
    float wr[64];
    {
        const float* wp = whh + ((size_t)d << 18) +
                          (size_t)(g * 256 + b * 64 + L) * 256 + c * 64;
#pragma unroll
        for (int i = 0; i < 16; i++) {
            float4 v = ((const float4*)wp)[i];
            wr[4*i+0] = v.x; wr[4*i+1] = v.y; wr[4*i+2] = v.z; wr[4*i+3] = v.w;
        }
    }
    unsigned long long* mypairs = pairs + (size_t)d * 512;
    const float* xgd = xg + ((size_t)d << 21);

    float cst = 0.f;
    float xgp[4] = {0.f, 0.f, 0.f, 0.f};
    if (w == 15) {
        stage[1][b*64 + L] = 0.f;   // h(0) own chunk for step 1
        int t0 = (d == 0) ? 0 : (T_LEN - 1);
#pragma unroll
        for (int g2 = 0; g2 < 4; g2++)
            xgp[g2] = xgd[((size_t)t0 << 10) + g2*256 + b*64 + L];
    }
    const int pc = (w < 3) ? (w + (w >= b)) : 0;  // probe chunk (remote)

    for (int s = 1; s <= T_LEN; s++) {
        const int par = s & 1;
        if (w < 3) {
            unsigned long long* pp = mypairs + ((s-1) & 1) * 256 + pc*64 + L;
            const unsigned tagexp = (unsigned)(s - 1);
            unsigned long long v;
            for (;;) {
                v = __hip_atomic_load(pp, __ATOMIC_RELAXED, __HIP_MEMORY_SCOPE_AGENT);
                if (__all((unsigned)(v >> 32) == tagexp)) break;
            }
            stage[par][pc*64 + L] = __uint_as_float((unsigned)v);
        }
        __syncthreads();  // h(s-1) complete in stage[par]

        const float4* hv = (const float4*)&stage[par][c*64];
        float a0 = 0.f, a1 = 0.f;
#pragma unroll
        for (int k4 = 0; k4 < 8; k4++) {
            float4 h4 = hv[k4];
            a0 = fmaf(h4.x, wr[4*k4+0], a0); a0 = fmaf(h4.y, wr[4*k4+1], a0);
            a0 = fmaf(h4.z, wr[4*k4+2], a0); a0 = fmaf(h4.w, wr[4*k4+3], a0);
        }
#pragma unroll
        for (int k4 = 8; k4 < 16; k4++) {
            float4 h4 = hv[k4];
            a1 = fmaf(h4.x, wr[4*k4+0], a1); a1 = fmaf(h4.y, wr[4*k4+1], a1);
            a1 = fmaf(h4.z, wr[4*k4+2], a1); a1 = fmaf(h4.w, wr[4*k4+3], a1);
        }
        parts[w][L] = a0 + a1;
        __syncthreads();

        if (w == 15) {
            float G[4];
#pragma unroll
            for (int g2 = 0; g2 < 4; g2++)
                G[g2] = parts[g2*4+0][L] + parts[g2*4+1][L] +
                        parts[g2*4+2][L] + parts[g2*4+3][L] + xgp[g2];
            float ig = 1.f / (1.f + __expf(-G[0]));
            float fg = 1.f / (1.f + __expf(-G[1]));
            float e2 = __expf(2.f * G[2]);
            float tg = (e2 - 1.f) / (e2 + 1.f);
            float og = 1.f / (1.f + __expf(-G[3]));
            cst = fg * cst + ig * tg;
            float ec = __expf(2.f * cst);
            float th = (ec - 1.f) / (ec + 1.f);
            float h = og * th;
            // publish ASAP (remote blocks are waiting on this)
            __hip_atomic_store(mypairs + par*256 + b*64 + L,
                ((unsigned long long)(unsigned)s << 32) | (unsigned long long)__float_as_uint(h),
                __ATOMIC_RELAXED, __HIP_MEMORY_SCOPE_AGENT);
            stage[1 - par][b*64 + L] = h;   // own chunk for step s+1
            int t = (d == 0) ? (s - 1) : (T_LEN - s);
            xout[(size_t)t * 512 + d*256 + b*64 + L] = h;
            int tn = (d == 0) ? ((s < T_LEN) ? s : (T_LEN - 1))
                              : ((s < T_LEN) ? (T_LEN - 1 - s) : 0);
#pragma unroll
            for (int g2 = 0; g2 < 4; g2++)
                xgp[g2] = xgd[((size_t)tn << 10) + g2*256 + b*64 + L];
        }
    }
}

// ---------------------------------------------------------------------------
// feats[t][n] = dot(x2[t], Wout[n]) + bout[n]
// ---------------------------------------------------------------------------
__global__ __launch_bounds__(64) void feats_kern(
    const float* __restrict__ x2, const float* __restrict__ Wout,
    const float* __restrict__ bout, float* __restrict__ feats)
{
    const int t = blockIdx.x;
    __shared__ __align__(16) float xr[512];
    for (int i = threadIdx.x; i < 128; i += 64)
        ((float4*)xr)[i] = ((const float4*)(x2 + (size_t)t * 512))[i];
    __syncthreads();
    const int n = threadIdx.x;
    if (n < K_TAG) {
        const float4* wrow = (const float4*)(Wout + (size_t)n * 512);
        float acc = 0.f;
#pragma unroll 8
        for (int k4 = 0; k4 < 128; k4++) {
            float4 wv = wrow[k4];
            float4 xv = ((const float4*)xr)[k4];
            acc = fmaf(wv.x, xv.x, acc); acc = fmaf(wv.y, xv.y, acc);
            acc = fmaf(wv.z, xv.z, acc); acc = fmaf(wv.w, xv.w, acc);
        }
        feats[t * K_TAG + n] = acc + bout[n];
    }
}

// ---------------------------------------------------------------------------
// Viterbi: single wave. lane n holds fv[n]; trans[n][p] in VGPRs.
// bptrs -> global; origin checkpoints every 128 steps enable parallel backtrack.
// ---------------------------------------------------------------------------
__global__ __launch_bounds__(64) void viterbi_kern(
    const float* __restrict__ feats, const float* __restrict__ trans,
    unsigned char* __restrict__ bptr, int* __restrict__ bnd,
    float* __restrict__ out)
{
    const int lane = threadIdx.x;
    const bool act = lane < K_TAG;
    float tr[K_TAG];
#pragma unroll
    for (int p = 0; p < K_TAG; p++)
        tr[p] = act ? trans[lane * K_TAG + p] : -3.0e38f;

    float fv = (lane == START_TAG) ? 0.f : NEG_VAL;
    int orig = lane;
    float feat = act ? feats[lane] : 0.f;

    for (int t = 0; t < T_LEN; t++) {
        float featn = (act && (t + 1 < T_LEN)) ? feats[(t + 1) * K_TAG + lane] : 0.f;
        float m = -3.0e38f; int bp = 0;
#pragma unroll
        for (int p = 0; p < K_TAG; p++) {
            float sp = __uint_as_float(__builtin_amdgcn_readlane(__float_as_uint(fv), p));
            float sc = sp + tr[p];
            if (sc > m) { m = sc; bp = p; }
        }
        fv = m + feat;
        feat = featn;
        if (act) bptr[t * K_TAG + lane] = (unsigned char)bp;
        orig = __shfl(orig, bp);
        if ((t & 127) == 127) {
            if (act) bnd[(t >> 7) * K_TAG + lane] = orig;
            orig = lane;
        }
    }
    float term = fv + (act ? trans[END_TAG * K_TAG + lane] : -3.0e38f);
    float bm = -3.0e38f; int bl = 0;
#pragma unroll
    for (int p = 0; p < K_TAG; p++) {
        float v = __uint_as_float(__builtin_amdgcn_readlane(__float_as_uint(term), p));
        if (v > bm) { bm = v; bl = p; }
    }
    if (lane == 0) out[0] = bm;

    __shared__ int sb[16];
    if (lane == 0) {
        int s = bl;
        sb[15] = s;
        for (int k = 15; k >= 1; k--) { s = bnd[k * K_TAG + s]; sb[k - 1] = s; }
    }
    __syncthreads();
    if (lane < 16) {
        int s = sb[lane];
        for (int t = lane * 128 + 127; t >= lane * 128; t--) {
            out[1 + t] = (float)s;
            s = (int)bptr[t * K_TAG + s];
        }
    }
}

// ---------------------------------------------------------------------------
extern "C" void kernel_launch(void* const* d_in, const int* in_sizes, int n_in,
                              void* d_out, int out_size, void* d_ws, size_t ws_size,
                              hipStream_t stream) {
    const int*   sent = (const int*)d_in[0];
    const float* emb  = (const float*)d_in[1];
    const float* wih  = (const float*)d_in[2];   // (2,2,1024,512)
    const float* whh  = (const float*)d_in[3];   // (2,2,1024,256)
    const float* bih  = (const float*)d_in[4];   // (2,2,1024)
    const float* bhh  = (const float*)d_in[5];
    const float* Wout = (const float*)d_in[6];   // (48,512)
    const float* bout = (const float*)d_in[7];   // (48,)
    const float* trans= (const float*)d_in[8];   // (48,48)
    float* out = (float*)d_out;

    float* ws = (float*)d_ws;
    float* xg    = ws;                       // 2*2048*1024 = 4194304 floats
    float* x1    = xg + 4194304;             // 2048*512
    float* x2    = x1 + 1048576;             // 2048*512
    float* feats = x2 + 1048576;             // 2048*48 = 98304
    unsigned long long* pairs = (unsigned long long*)(feats + 98304); // 2 phases * 1024
    unsigned char* bptr = (unsigned char*)(pairs + 2048);             // 2048*48 bytes
    int* bnd = (int*)(bptr + T_LEN * K_TAG);                          // 16*48 ints

    // zero sync tags (ws is poisoned 0xAA before every timed launch)
    hipMemsetAsync(pairs, 0, 2048 * sizeof(unsigned long long), stream);

    dim3 gg(32, 32);
    // layer 1: xg = gather(emb,sent) @ wih[0,*].T + bias
    gemm_xg<<<gg, 256, 0, stream>>>(emb, sent, wih, bih, bhh, xg, 1);
    lstm_pass<<<8, 1024, 0, stream>>>(xg, whh, x1, pairs);
    // layer 2
    gemm_xg<<<gg, 256, 0, stream>>>(x1, nullptr, wih + (1 << 20),
                                    bih + 2048, bhh + 2048, xg, 0);
    lstm_pass<<<8, 1024, 0, stream>>>(xg, whh + (1 << 19), x2, pairs + 1024);
    // projection + viterbi
    feats_kern<<<T_LEN, 64, 0, stream>>>(x2, Wout, bout, feats);
    viterbi_kern<<<1, 64, 0, stream>>>(feats, trans, bptr, bnd, out);
}

// Round 4
// 10579.234 us; speedup vs baseline: 1.0244x; 1.0244x over previous
//
#include <hip/hip_runtime.h>
#include <hip/hip_bf16.h>

// Problem constants
#define T_LEN 2048
#define E_DIM 512
#define H_DIM 256
#define K_TAG 48
#define START_TAG 46
#define END_TAG 47
#define NEG_VAL -10000.0f

// ---------------------------------------------------------------------------
// GEMM: out[d][t][row] = dot(A[t][0:512], W[d*1024+row][0:512]) + bih[n]+bhh[n]
// A is either x (2048x512) or gathered embedding rows (useGather).
// W = wih for one layer, flattened (2048 rows x 512).
// out index: ((d*2048 + t)<<10) + row   (n = d*1024+row)
// ---------------------------------------------------------------------------
__global__ __launch_bounds__(256) void gemm_xg(
    const float* __restrict__ Abase, const int* __restrict__ sent,
    const float* __restrict__ Bw, const float* __restrict__ bih,
    const float* __restrict__ bhh, float* __restrict__ out, int useGather)
{
    __shared__ float As[16][68];
    __shared__ float Bs[16][68];
    const int tx = threadIdx.x & 15, ty = threadIdx.x >> 4;
    const int t0 = blockIdx.y * 64, n0 = blockIdx.x * 64;
    // staging: thread -> (row r, 4 consecutive k)
    const int r  = threadIdx.x >> 2;        // 0..63
    const int kq = (threadIdx.x & 3) * 4;   // 0,4,8,12
    const float* arow;
    if (useGather) arow = Abase + (size_t)sent[t0 + r] * 512 + kq;
    else           arow = Abase + (size_t)(t0 + r) * 512 + kq;
    const float* brow = Bw + (size_t)(n0 + r) * 512 + kq;

    float acc[4][4];
#pragma unroll
    for (int i = 0; i < 4; i++)
#pragma unroll
        for (int j = 0; j < 4; j++) acc[i][j] = 0.f;

    for (int k0 = 0; k0 < 512; k0 += 16) {
        float4 a4 = *(const float4*)(arow + k0);
        float4 b4 = *(const float4*)(brow + k0);
        __syncthreads();
        As[kq+0][r] = a4.x; As[kq+1][r] = a4.y; As[kq+2][r] = a4.z; As[kq+3][r] = a4.w;
        Bs[kq+0][r] = b4.x; Bs[kq+1][r] = b4.y; Bs[kq+2][r] = b4.z; Bs[kq+3][r] = b4.w;
        __syncthreads();
#pragma unroll
        for (int k = 0; k < 16; k++) {
            float4 av = *(const float4*)&As[k][ty*4];
            float4 bv = *(const float4*)&Bs[k][tx*4];
            acc[0][0] = fmaf(av.x, bv.x, acc[0][0]); acc[0][1] = fmaf(av.x, bv.y, acc[0][1]);
            acc[0][2] = fmaf(av.x, bv.z, acc[0][2]); acc[0][3] = fmaf(av.x, bv.w, acc[0][3]);
            acc[1][0] = fmaf(av.y, bv.x, acc[1][0]); acc[1][1] = fmaf(av.y, bv.y, acc[1][1]);
            acc[1][2] = fmaf(av.y, bv.z, acc[1][2]); acc[1][3] = fmaf(av.y, bv.w, acc[1][3]);
            acc[2][0] = fmaf(av.z, bv.x, acc[2][0]); acc[2][1] = fmaf(av.z, bv.y, acc[2][1]);
            acc[2][2] = fmaf(av.z, bv.z, acc[2][2]); acc[2][3] = fmaf(av.z, bv.w, acc[2][3]);
            acc[3][0] = fmaf(av.w, bv.x, acc[3][0]); acc[3][1] = fmaf(av.w, bv.y, acc[3][1]);
            acc[3][2] = fmaf(av.w, bv.z, acc[3][2]); acc[3][3] = fmaf(av.w, bv.w, acc[3][3]);
        }
    }
#pragma unroll
    for (int i = 0; i < 4; i++) {
        int t = t0 + ty*4 + i;
#pragma unroll
        for (int j = 0; j < 4; j++) {
            int n = n0 + tx*4 + j;
            float b = bih[n] + bhh[n];
            out[((size_t)((n >> 10) * 2048 + t) << 10) + (n & 1023)] = acc[i][j] + b;
        }
    }
}

// ---------------------------------------------------------------------------
// LSTM recurrence. Grid = 8 blocks: d = bx>>2 (0 fwd, 1 bwd), b = bx&3 (quad).
// Block owns 64 hidden units [64b,64b+64). wave w: gate g=w>>2, h-chunk c=w&3.
// Weights (256 rows x 256 cols fp32 = 256KB) live in VGPRs (64/thread).
//
// OCCUPANCY/VGPR HISTORY:
//   R0: __launch_bounds__(1024)    -> VGPR_Count=56, ~1.92us/step
//   R1: __launch_bounds__(1024,4)  -> still 56 (2nd arg is only a MIN)
//   R2: amdgpu_waves_per_eu(4,4)   -> VGPR 60, SGPR 112: attribute honored,
//       budget=128 available, allocator STILL won't hold wr[]. Diagnosis:
//       whh loads are invariant loads (const __restrict__) => LLVM regalloc
//       REMATERIALIZES them inside the loop instead of keeping 64 live regs.
//       No budget attribute can fix remat; the loads must become opaque defs.
//   R3: empty inline-asm tie per element ("+v") after the preload. Asm defs
//       cannot be re-executed by the allocator => wr[] must stay resident
//       (or spill, but 64+~35 temps < 128 budget so residency is cheapest).
// Cross-block h exchange: tagged {h,step} 8B relaxed AGENT atomics, 2 slots.
// ---------------------------------------------------------------------------
__global__ __launch_bounds__(1024)
__attribute__((amdgpu_waves_per_eu(4, 4)))
void lstm_pass(
    const float* __restrict__ xg,   // (2, T, 1024) for this layer
    const float* __restrict__ whh,  // (2, 1024, 256) for this layer
    float* __restrict__ xout,       // (T, 512) concat [hf, hb]
    unsigned long long* __restrict__ pairs) // (2 dirs, 2 slots, 256)
{
    const int tid = threadIdx.x;
    const int w = tid >> 6, L = tid & 63;
    const int d = blockIdx.x >> 2, b = blockIdx.x & 3;
    const int g = w >> 2, c = w & 3;

    __shared__ __align__(16) float stage[2][256];
    __shared__ float parts[16][64];

    // weight preload: row = g*256 + b*64 + L, cols [c*64, c*64+64)
    float wr[64];
    {
        const float* wp = whh + ((size_t)d << 18) +
                          (size_t)(g * 256 + b * 64 + L) * 256 + c * 64;
#pragma unroll
        for (int i = 0; i < 16; i++) {
            float4 v = ((const float4*)wp)[i];
            wr[4*i+0] = v.x; wr[4*i+1] = v.y; wr[4*i+2] = v.z; wr[4*i+3] = v.w;
        }
    }
    // Defeat invariant-load rematerialization: opaque def per element.
#pragma unroll
    for (int i = 0; i < 64; i++)
        asm volatile("" : "+v"(wr[i]));

    unsigned long long* mypairs = pairs + (size_t)d * 512;
    const float* xgd = xg + ((size_t)d << 21);

    float cst = 0.f;
    float xgp[4] = {0.f, 0.f, 0.f, 0.f};
    if (w == 15) {
        stage[1][b*64 + L] = 0.f;   // h(0) own chunk for step 1
        int t0 = (d == 0) ? 0 : (T_LEN - 1);
#pragma unroll
        for (int g2 = 0; g2 < 4; g2++)
            xgp[g2] = xgd[((size_t)t0 << 10) + g2*256 + b*64 + L];
    }
    const int pc = (w < 3) ? (w + (w >= b)) : 0;  // probe chunk (remote)

    for (int s = 1; s <= T_LEN; s++) {
        const int par = s & 1;
        if (w < 3) {
            unsigned long long* pp = mypairs + ((s-1) & 1) * 256 + pc*64 + L;
            const unsigned tagexp = (unsigned)(s - 1);
            unsigned long long v;
            for (;;) {
                v = __hip_atomic_load(pp, __ATOMIC_RELAXED, __HIP_MEMORY_SCOPE_AGENT);
                if (__all((unsigned)(v >> 32) == tagexp)) break;
            }
            stage[par][pc*64 + L] = __uint_as_float((unsigned)v);
        }
        __syncthreads();  // h(s-1) complete in stage[par]

        const float4* hv = (const float4*)&stage[par][c*64];
        float a0 = 0.f, a1 = 0.f;
#pragma unroll
        for (int k4 = 0; k4 < 8; k4++) {
            float4 h4 = hv[k4];
            a0 = fmaf(h4.x, wr[4*k4+0], a0); a0 = fmaf(h4.y, wr[4*k4+1], a0);
            a0 = fmaf(h4.z, wr[4*k4+2], a0); a0 = fmaf(h4.w, wr[4*k4+3], a0);
        }
#pragma unroll
        for (int k4 = 8; k4 < 16; k4++) {
            float4 h4 = hv[k4];
            a1 = fmaf(h4.x, wr[4*k4+0], a1); a1 = fmaf(h4.y, wr[4*k4+1], a1);
            a1 = fmaf(h4.z, wr[4*k4+2], a1); a1 = fmaf(h4.w, wr[4*k4+3], a1);
        }
        parts[w][L] = a0 + a1;
        __syncthreads();

        if (w == 15) {
            float G[4];
#pragma unroll
            for (int g2 = 0; g2 < 4; g2++)
                G[g2] = parts[g2*4+0][L] + parts[g2*4+1][L] +
                        parts[g2*4+2][L] + parts[g2*4+3][L] + xgp[g2];
            float ig = 1.f / (1.f + __expf(-G[0]));
            float fg = 1.f / (1.f + __expf(-G[1]));
            float e2 = __expf(2.f * G[2]);
            float tg = (e2 - 1.f) / (e2 + 1.f);
            float og = 1.f / (1.f + __expf(-G[3]));
            cst = fg * cst + ig * tg;
            float ec = __expf(2.f * cst);
            float th = (ec - 1.f) / (ec + 1.f);
            float h = og * th;
            // publish ASAP (remote blocks are waiting on this)
            __hip_atomic_store(mypairs + par*256 + b*64 + L,
                ((unsigned long long)(unsigned)s << 32) | (unsigned long long)__float_as_uint(h),
                __ATOMIC_RELAXED, __HIP_MEMORY_SCOPE_AGENT);
            stage[1 - par][b*64 + L] = h;   // own chunk for step s+1
            int t = (d == 0) ? (s - 1) : (T_LEN - s);
            xout[(size_t)t * 512 + d*256 + b*64 + L] = h;
            int tn = (d == 0) ? ((s < T_LEN) ? s : (T_LEN - 1))
                              : ((s < T_LEN) ? (T_LEN - 1 - s) : 0);
#pragma unroll
            for (int g2 = 0; g2 < 4; g2++)
                xgp[g2] = xgd[((size_t)tn << 10) + g2*256 + b*64 + L];
        }
    }
}

// ---------------------------------------------------------------------------
// feats[t][n] = dot(x2[t], Wout[n]) + bout[n]
// ---------------------------------------------------------------------------
__global__ __launch_bounds__(64) void feats_kern(
    const float* __restrict__ x2, const float* __restrict__ Wout,
    const float* __restrict__ bout, float* __restrict__ feats)
{
    const int t = blockIdx.x;
    __shared__ __align__(16) float xr[512];
    for (int i = threadIdx.x; i < 128; i += 64)
        ((float4*)xr)[i] = ((const float4*)(x2 + (size_t)t * 512))[i];
    __syncthreads();
    const int n = threadIdx.x;
    if (n < K_TAG) {
        const float4* wrow = (const float4*)(Wout + (size_t)n * 512);
        float acc = 0.f;
#pragma unroll 8
        for (int k4 = 0; k4 < 128; k4++) {
            float4 wv = wrow[k4];
            float4 xv = ((const float4*)xr)[k4];
            acc = fmaf(wv.x, xv.x, acc); acc = fmaf(wv.y, xv.y, acc);
            acc = fmaf(wv.z, xv.z, acc); acc = fmaf(wv.w, xv.w, acc);
        }
        feats[t * K_TAG + n] = acc + bout[n];
    }
}

// ---------------------------------------------------------------------------
// Viterbi: single wave. lane n holds fv[n]; trans[n][p] in VGPRs.
// bptrs -> global; origin checkpoints every 128 steps enable parallel backtrack.
// ---------------------------------------------------------------------------
__global__ __launch_bounds__(64) void viterbi_kern(
    const float* __restrict__ feats, const float* __restrict__ trans,
    unsigned char* __restrict__ bptr, int* __restrict__ bnd,
    float* __restrict__ out)
{
    const int lane = threadIdx.x;
    const bool act = lane < K_TAG;
    float tr[K_TAG];
#pragma unroll
    for (int p = 0; p < K_TAG; p++)
        tr[p] = act ? trans[lane * K_TAG + p] : -3.0e38f;

    float fv = (lane == START_TAG) ? 0.f : NEG_VAL;
    int orig = lane;
    float feat = act ? feats[lane] : 0.f;

    for (int t = 0; t < T_LEN; t++) {
        float featn = (act && (t + 1 < T_LEN)) ? feats[(t + 1) * K_TAG + lane] : 0.f;
        float m = -3.0e38f; int bp = 0;
#pragma unroll
        for (int p = 0; p < K_TAG; p++) {
            float sp = __uint_as_float(__builtin_amdgcn_readlane(__float_as_uint(fv), p));
            float sc = sp + tr[p];
            if (sc > m) { m = sc; bp = p; }
        }
        fv = m + feat;
        feat = featn;
        if (act) bptr[t * K_TAG + lane] = (unsigned char)bp;
        orig = __shfl(orig, bp);
        if ((t & 127) == 127) {
            if (act) bnd[(t >> 7) * K_TAG + lane] = orig;
            orig = lane;
        }
    }
    float term = fv + (act ? trans[END_TAG * K_TAG + lane] : -3.0e38f);
    float bm = -3.0e38f; int bl = 0;
#pragma unroll
    for (int p = 0; p < K_TAG; p++) {
        float v = __uint_as_float(__builtin_amdgcn_readlane(__float_as_uint(term), p));
        if (v > bm) { bm = v; bl = p; }
    }
    if (lane == 0) out[0] = bm;

    __shared__ int sb[16];
    if (lane == 0) {
        int s = bl;
        sb[15] = s;
        for (int k = 15; k >= 1; k--) { s = bnd[k * K_TAG + s]; sb[k - 1] = s; }
    }
    __syncthreads();
    if (lane < 16) {
        int s = sb[lane];
        for (int t = lane * 128 + 127; t >= lane * 128; t--) {
            out[1 + t] = (float)s;
            s = (int)bptr[t * K_TAG + s];
        }
    }
}

// ---------------------------------------------------------------------------
extern "C" void kernel_launch(void* const* d_in, const int* in_sizes, int n_in,
                              void* d_out, int out_size, void* d_ws, size_t ws_size,
                              hipStream_t stream) {
    const int*   sent = (const int*)d_in[0];
    const float* emb  = (const float*)d_in[1];
    const float* wih  = (const float*)d_in[2];   // (2,2,1024,512)
    const float* whh  = (const float*)d_in[3];   // (2,2,1024,256)
    const float* bih  = (const float*)d_in[4];   // (2,2,1024)
    const float* bhh  = (const float*)d_in[5];
    const float* Wout = (const float*)d_in[6];   // (48,512)
    const float* bout = (const float*)d_in[7];   // (48,)
    const float* trans= (const float*)d_in[8];   // (48,48)
    float* out = (float*)d_out;

    float* ws = (float*)d_ws;
    float* xg    = ws;                       // 2*2048*1024 = 4194304 floats
    float* x1    = xg + 4194304;             // 2048*512
    float* x2    = x1 + 1048576;             // 2048*512
    float* feats = x2 + 1048576;             // 2048*48 = 98304
    unsigned long long* pairs = (unsigned long long*)(feats + 98304); // 2 phases * 1024
    unsigned char* bptr = (unsigned char*)(pairs + 2048);             // 2048*48 bytes
    int* bnd = (int*)(bptr + T_LEN * K_TAG);                          // 16*48 ints

    // zero sync tags (ws is poisoned 0xAA before every timed launch)
    hipMemsetAsync(pairs, 0, 2048 * sizeof(unsigned long long), stream);

    dim3 gg(32, 32);
    // layer 1: xg = gather(emb,sent) @ wih[0,*].T + bias
    gemm_xg<<<gg, 256, 0, stream>>>(emb, sent, wih, bih, bhh, xg, 1);
    lstm_pass<<<8, 1024, 0, stream>>>(xg, whh, x1, pairs);
    // layer 2
    gemm_xg<<<gg, 256, 0, stream>>>(x1, nullptr, wih + (1 << 20),
                                    bih + 2048, bhh + 2048, xg, 0);
    lstm_pass<<<8, 1024, 0, stream>>>(xg, whh + (1 << 19), x2, pairs + 1024);
    // projection + viterbi
    feats_kern<<<T_LEN, 64, 0, stream>>>(x2, Wout, bout, feats);
    viterbi_kern<<<1, 64, 0, stream>>>(feats, trans, bptr, bnd, out);
}

// Round 5
// 10379.733 us; speedup vs baseline: 1.0440x; 1.0192x over previous
//
#include <hip/hip_runtime.h>
#include <hip/hip_bf16.h>

// Problem constants
#define T_LEN 2048
#define E_DIM 512
#define H_DIM 256
#define K_TAG 48
#define START_TAG 46
#define END_TAG 47
#define NEG_VAL -10000.0f

// ---------------------------------------------------------------------------
// GEMM: out[d][t][row] = dot(A[t][0:512], W[d*1024+row][0:512]) + bih[n]+bhh[n]
// ---------------------------------------------------------------------------
__global__ __launch_bounds__(256) void gemm_xg(
    const float* __restrict__ Abase, const int* __restrict__ sent,
    const float* __restrict__ Bw, const float* __restrict__ bih,
    const float* __restrict__ bhh, float* __restrict__ out, int useGather)
{
    __shared__ float As[16][68];
    __shared__ float Bs[16][68];
    const int tx = threadIdx.x & 15, ty = threadIdx.x >> 4;
    const int t0 = blockIdx.y * 64, n0 = blockIdx.x * 64;
    const int r  = threadIdx.x >> 2;        // 0..63
    const int kq = (threadIdx.x & 3) * 4;   // 0,4,8,12
    const float* arow;
    if (useGather) arow = Abase + (size_t)sent[t0 + r] * 512 + kq;
    else           arow = Abase + (size_t)(t0 + r) * 512 + kq;
    const float* brow = Bw + (size_t)(n0 + r) * 512 + kq;

    float acc[4][4];
#pragma unroll
    for (int i = 0; i < 4; i++)
#pragma unroll
        for (int j = 0; j < 4; j++) acc[i][j] = 0.f;

    for (int k0 = 0; k0 < 512; k0 += 16) {
        float4 a4 = *(const float4*)(arow + k0);
        float4 b4 = *(const float4*)(brow + k0);
        __syncthreads();
        As[kq+0][r] = a4.x; As[kq+1][r] = a4.y; As[kq+2][r] = a4.z; As[kq+3][r] = a4.w;
        Bs[kq+0][r] = b4.x; Bs[kq+1][r] = b4.y; Bs[kq+2][r] = b4.z; Bs[kq+3][r] = b4.w;
        __syncthreads();
#pragma unroll
        for (int k = 0; k < 16; k++) {
            float4 av = *(const float4*)&As[k][ty*4];
            float4 bv = *(const float4*)&Bs[k][tx*4];
            acc[0][0] = fmaf(av.x, bv.x, acc[0][0]); acc[0][1] = fmaf(av.x, bv.y, acc[0][1]);
            acc[0][2] = fmaf(av.x, bv.z, acc[0][2]); acc[0][3] = fmaf(av.x, bv.w, acc[0][3]);
            acc[1][0] = fmaf(av.y, bv.x, acc[1][0]); acc[1][1] = fmaf(av.y, bv.y, acc[1][1]);
            acc[1][2] = fmaf(av.y, bv.z, acc[1][2]); acc[1][3] = fmaf(av.y, bv.w, acc[1][3]);
            acc[2][0] = fmaf(av.z, bv.x, acc[2][0]); acc[2][1] = fmaf(av.z, bv.y, acc[2][1]);
            acc[2][2] = fmaf(av.z, bv.z, acc[2][2]); acc[2][3] = fmaf(av.z, bv.w, acc[2][3]);
            acc[3][0] = fmaf(av.w, bv.x, acc[3][0]); acc[3][1] = fmaf(av.w, bv.y, acc[3][1]);
            acc[3][2] = fmaf(av.w, bv.z, acc[3][2]); acc[3][3] = fmaf(av.w, bv.w, acc[3][3]);
        }
    }
#pragma unroll
    for (int i = 0; i < 4; i++) {
        int t = t0 + ty*4 + i;
#pragma unroll
        for (int j = 0; j < 4; j++) {
            int n = n0 + tx*4 + j;
            float b = bih[n] + bhh[n];
            out[((size_t)((n >> 10) * 2048 + t) << 10) + (n & 1023)] = acc[i][j] + b;
        }
    }
}

// ---------------------------------------------------------------------------
// LSTM recurrence. Grid = 8 blocks: d = bx>>2 (dir), b = bx&3 (h-quad).
// Block owns 64 hidden units. 512 threads = 8 waves: gate g=w>>1, k-half c=w&1.
// Each thread holds 128 whh weights (row g*256+b*64+L, cols c*128..+128).
//
// VGPR HISTORY (why 512 threads):
//   R0-R3: 1024-thread blocks (16 waves) => per-thread budget hard-capped at
//   128. 64 resident weights + ~60 loop temps = 124/128: allocator had no
//   headroom, so it rematerialized (R0-R2) or scratch-spilled (R3 asm ties)
//   the weights; VGPR_Count stuck at 56-60, ~1.9us/step from per-step VMEM.
//   R4: 8 waves + amdgpu_waves_per_eu(2,2) => budget 256. Same 256KB weights
//   per CU, now 128/thread + ~60 temps ~= 190 <= 256: residency is cheapest.
// Cross-block h exchange: tagged {h,step} 8B relaxed AGENT atomics, 2 slots.
// ---------------------------------------------------------------------------
__global__ __launch_bounds__(512)
__attribute__((amdgpu_waves_per_eu(2, 2)))
void lstm_pass(
    const float* __restrict__ xg,   // (2, T, 1024) for this layer
    const float* __restrict__ whh,  // (2, 1024, 256) for this layer
    float* __restrict__ xout,       // (T, 512) concat [hf, hb]
    unsigned long long* __restrict__ pairs) // (2 dirs, 2 slots, 256)
{
    const int tid = threadIdx.x;
    const int w = tid >> 6, L = tid & 63;
    const int d = blockIdx.x >> 2, b = blockIdx.x & 3;
    const int g = w >> 1, c = w & 1;

    __shared__ __align__(16) float stage[2][256];
    __shared__ float parts[8][64];

    // weight preload: row = g*256 + b*64 + L, cols [c*128, c*128+128)
    float wr[128];
    {
        const float* wp = whh + ((size_t)d << 18) +
                          (size_t)(g * 256 + b * 64 + L) * 256 + c * 128;
#pragma unroll
        for (int i = 0; i < 32; i++) {
            float4 v = ((const float4*)wp)[i];
            wr[4*i+0] = v.x; wr[4*i+1] = v.y; wr[4*i+2] = v.z; wr[4*i+3] = v.w;
        }
    }
    // Defensive: forbid invariant-load remat of the weights.
#pragma unroll
    for (int i = 0; i < 128; i++)
        asm volatile("" : "+v"(wr[i]));

    unsigned long long* mypairs = pairs + (size_t)d * 512;
    const float* xgd = xg + ((size_t)d << 21);

    float cst = 0.f;
    float xgp[4] = {0.f, 0.f, 0.f, 0.f};
    if (w == 7) {
        stage[1][b*64 + L] = 0.f;   // h(0) own chunk for step 1
        int t0 = (d == 0) ? 0 : (T_LEN - 1);
#pragma unroll
        for (int g2 = 0; g2 < 4; g2++)
            xgp[g2] = xgd[((size_t)t0 << 10) + g2*256 + b*64 + L];
    }
    const int pc = (w < 3) ? (w + (w >= b)) : 0;  // probe chunk (remote)

    for (int s = 1; s <= T_LEN; s++) {
        const int par = s & 1;
        if (w < 3) {
            unsigned long long* pp = mypairs + ((s-1) & 1) * 256 + pc*64 + L;
            const unsigned tagexp = (unsigned)(s - 1);
            unsigned long long v;
            for (;;) {
                v = __hip_atomic_load(pp, __ATOMIC_RELAXED, __HIP_MEMORY_SCOPE_AGENT);
                if (__all((unsigned)(v >> 32) == tagexp)) break;
            }
            stage[par][pc*64 + L] = __uint_as_float((unsigned)v);
        }
        __syncthreads();  // h(s-1) complete in stage[par]

        const float4* hv = (const float4*)&stage[par][c*128];
        float acc[4] = {0.f, 0.f, 0.f, 0.f};
#pragma unroll
        for (int k4 = 0; k4 < 32; k4++) {
            float4 h4 = hv[k4];
            acc[k4 & 3] = fmaf(h4.x, wr[4*k4+0], acc[k4 & 3]);
            acc[k4 & 3] = fmaf(h4.y, wr[4*k4+1], acc[k4 & 3]);
            acc[k4 & 3] = fmaf(h4.z, wr[4*k4+2], acc[k4 & 3]);
            acc[k4 & 3] = fmaf(h4.w, wr[4*k4+3], acc[k4 & 3]);
        }
        parts[w][L] = (acc[0] + acc[1]) + (acc[2] + acc[3]);
        __syncthreads();

        if (w == 7) {
            float G[4];
#pragma unroll
            for (int g2 = 0; g2 < 4; g2++)
                G[g2] = parts[2*g2][L] + parts[2*g2+1][L] + xgp[g2];
            float ig = 1.f / (1.f + __expf(-G[0]));
            float fg = 1.f / (1.f + __expf(-G[1]));
            float e2 = __expf(2.f * G[2]);
            float tg = (e2 - 1.f) / (e2 + 1.f);
            float og = 1.f / (1.f + __expf(-G[3]));
            cst = fg * cst + ig * tg;
            float ec = __expf(2.f * cst);
            float th = (ec - 1.f) / (ec + 1.f);
            float h = og * th;
            // publish ASAP (remote blocks are waiting on this)
            __hip_atomic_store(mypairs + par*256 + b*64 + L,
                ((unsigned long long)(unsigned)s << 32) | (unsigned long long)__float_as_uint(h),
                __ATOMIC_RELAXED, __HIP_MEMORY_SCOPE_AGENT);
            stage[1 - par][b*64 + L] = h;   // own chunk for step s+1
            int t = (d == 0) ? (s - 1) : (T_LEN - s);
            xout[(size_t)t * 512 + d*256 + b*64 + L] = h;
            int tn = (d == 0) ? ((s < T_LEN) ? s : (T_LEN - 1))
                              : ((s < T_LEN) ? (T_LEN - 1 - s) : 0);
#pragma unroll
            for (int g2 = 0; g2 < 4; g2++)
                xgp[g2] = xgd[((size_t)tn << 10) + g2*256 + b*64 + L];
        }
    }
}

// ---------------------------------------------------------------------------
// feats[t][n] = dot(x2[t], Wout[n]) + bout[n]
// ---------------------------------------------------------------------------
__global__ __launch_bounds__(64) void feats_kern(
    const float* __restrict__ x2, const float* __restrict__ Wout,
    const float* __restrict__ bout, float* __restrict__ feats)
{
    const int t = blockIdx.x;
    __shared__ __align__(16) float xr[512];
    for (int i = threadIdx.x; i < 128; i += 64)
        ((float4*)xr)[i] = ((const float4*)(x2 + (size_t)t * 512))[i];
    __syncthreads();
    const int n = threadIdx.x;
    if (n < K_TAG) {
        const float4* wrow = (const float4*)(Wout + (size_t)n * 512);
        float acc = 0.f;
#pragma unroll 8
        for (int k4 = 0; k4 < 128; k4++) {
            float4 wv = wrow[k4];
            float4 xv = ((const float4*)xr)[k4];
            acc = fmaf(wv.x, xv.x, acc); acc = fmaf(wv.y, xv.y, acc);
            acc = fmaf(wv.z, xv.z, acc); acc = fmaf(wv.w, xv.w, acc);
        }
        feats[t * K_TAG + n] = acc + bout[n];
    }
}

// ---------------------------------------------------------------------------
// Viterbi: single wave. lane n holds fv[n]; trans[n][p] in VGPRs.
// ---------------------------------------------------------------------------
__global__ __launch_bounds__(64) void viterbi_kern(
    const float* __restrict__ feats, const float* __restrict__ trans,
    unsigned char* __restrict__ bptr, int* __restrict__ bnd,
    float* __restrict__ out)
{
    const int lane = threadIdx.x;
    const bool act = lane < K_TAG;
    float tr[K_TAG];
#pragma unroll
    for (int p = 0; p < K_TAG; p++)
        tr[p] = act ? trans[lane * K_TAG + p] : -3.0e38f;

    float fv = (lane == START_TAG) ? 0.f : NEG_VAL;
    int orig = lane;
    float feat = act ? feats[lane] : 0.f;

    for (int t = 0; t < T_LEN; t++) {
        float featn = (act && (t + 1 < T_LEN)) ? feats[(t + 1) * K_TAG + lane] : 0.f;
        float m = -3.0e38f; int bp = 0;
#pragma unroll
        for (int p = 0; p < K_TAG; p++) {
            float sp = __uint_as_float(__builtin_amdgcn_readlane(__float_as_uint(fv), p));
            float sc = sp + tr[p];
            if (sc > m) { m = sc; bp = p; }
        }
        fv = m + feat;
        feat = featn;
        if (act) bptr[t * K_TAG + lane] = (unsigned char)bp;
        orig = __shfl(orig, bp);
        if ((t & 127) == 127) {
            if (act) bnd[(t >> 7) * K_TAG + lane] = orig;
            orig = lane;
        }
    }
    float term = fv + (act ? trans[END_TAG * K_TAG + lane] : -3.0e38f);
    float bm = -3.0e38f; int bl = 0;
#pragma unroll
    for (int p = 0; p < K_TAG; p++) {
        float v = __uint_as_float(__builtin_amdgcn_readlane(__float_as_uint(term), p));
        if (v > bm) { bm = v; bl = p; }
    }
    if (lane == 0) out[0] = bm;

    __shared__ int sb[16];
    if (lane == 0) {
        int s = bl;
        sb[15] = s;
        for (int k = 15; k >= 1; k--) { s = bnd[k * K_TAG + s]; sb[k - 1] = s; }
    }
    __syncthreads();
    if (lane < 16) {
        int s = sb[lane];
        for (int t = lane * 128 + 127; t >= lane * 128; t--) {
            out[1 + t] = (float)s;
            s = (int)bptr[t * K_TAG + s];
        }
    }
}

// ---------------------------------------------------------------------------
extern "C" void kernel_launch(void* const* d_in, const int* in_sizes, int n_in,
                              void* d_out, int out_size, void* d_ws, size_t ws_size,
                              hipStream_t stream) {
    const int*   sent = (const int*)d_in[0];
    const float* emb  = (const float*)d_in[1];
    const float* wih  = (const float*)d_in[2];   // (2,2,1024,512)
    const float* whh  = (const float*)d_in[3];   // (2,2,1024,256)
    const float* bih  = (const float*)d_in[4];   // (2,2,1024)
    const float* bhh  = (const float*)d_in[5];
    const float* Wout = (const float*)d_in[6];   // (48,512)
    const float* bout = (const float*)d_in[7];   // (48,)
    const float* trans= (const float*)d_in[8];   // (48,48)
    float* out = (float*)d_out;

    float* ws = (float*)d_ws;
    float* xg    = ws;                       // 2*2048*1024 = 4194304 floats
    float* x1    = xg + 4194304;             // 2048*512
    float* x2    = x1 + 1048576;             // 2048*512
    float* feats = x2 + 1048576;             // 2048*48 = 98304
    unsigned long long* pairs = (unsigned long long*)(feats + 98304); // 2 layers * 1024
    unsigned char* bptr = (unsigned char*)(pairs + 2048);             // 2048*48 bytes
    int* bnd = (int*)(bptr + T_LEN * K_TAG);                          // 16*48 ints

    // zero sync tags (ws is poisoned 0xAA before every timed launch)
    hipMemsetAsync(pairs, 0, 2048 * sizeof(unsigned long long), stream);

    dim3 gg(32, 32);
    // layer 1: xg = gather(emb,sent) @ wih[0,*].T + bias
    gemm_xg<<<gg, 256, 0, stream>>>(emb, sent, wih, bih, bhh, xg, 1);
    lstm_pass<<<8, 512, 0, stream>>>(xg, whh, x1, pairs);
    // layer 2
    gemm_xg<<<gg, 256, 0, stream>>>(x1, nullptr, wih + (1 << 20),
                                    bih + 2048, bhh + 2048, xg, 0);
    lstm_pass<<<8, 512, 0, stream>>>(xg, whh + (1 << 19), x2, pairs + 1024);
    // projection + viterbi
    feats_kern<<<T_LEN, 64, 0, stream>>>(x2, Wout, bout, feats);
    viterbi_kern<<<1, 64, 0, stream>>>(feats, trans, bptr, bnd, out);
}